// Round 2
// baseline (947.861 us; speedup 1.0000x reference)
//
#include <hip/hip_runtime.h>

// GCN 2-layer, N=100000, E=3200000, 13 -> 32 -> 16.
// Counting-sort edges by dst, then atomic-free per-node aggregation.
// Layer 1 aggregates BEFORE the GEMM (linearity): 16-ch messages both layers.
// All aggregation inputs pre-multiplied by dis[src]; dis[dst] applied per node.

constexpr int N_NODES = 100000;
constexpr int N_EDGES = 3200000;
constexpr int IN_CH  = 13;
constexpr int HID_CH = 32;
constexpr int LAT_CH = 16;

__global__ __launch_bounds__(256) void k_zero(int* __restrict__ cnt) {
    int i = blockIdx.x * 256 + threadIdx.x;
    if (i < N_NODES) cnt[i] = 0;
}

__global__ __launch_bounds__(256) void k_hist(const int* __restrict__ dst,
                                              int* __restrict__ cnt) {
    int e = blockIdx.x * 256 + threadIdx.x;
    if (e < N_EDGES) atomicAdd(&cnt[dst[e]], 1);
}

__global__ __launch_bounds__(256) void k_dis(const int* __restrict__ cnt,
                                             float* __restrict__ dis) {
    int i = blockIdx.x * 256 + threadIdx.x;
    if (i < N_NODES) dis[i] = rsqrtf((float)(cnt[i] + 1));  // +1 self-loop
}

// single-block exclusive scan of cnt -> off (N+1), cursor copy
__global__ __launch_bounds__(1024) void k_scan(const int* __restrict__ cnt,
                                               int* __restrict__ off,
                                               int* __restrict__ cursor) {
    __shared__ int lds[1024];
    const int CH = (N_NODES + 1023) / 1024;  // 98
    int tid = threadIdx.x;
    int base = tid * CH;
    int s = 0;
    for (int i = 0; i < CH; ++i) {
        int g = base + i;
        if (g < N_NODES) s += cnt[g];
    }
    lds[tid] = s;
    __syncthreads();
    for (int d = 1; d < 1024; d <<= 1) {   // Hillis-Steele inclusive
        int v = lds[tid];
        int u = (tid >= d) ? lds[tid - d] : 0;
        __syncthreads();
        lds[tid] = v + u;
        __syncthreads();
    }
    int run = (tid == 0) ? 0 : lds[tid - 1];
    for (int i = 0; i < CH; ++i) {
        int g = base + i;
        if (g < N_NODES) {
            off[g] = run;
            cursor[g] = run;
            run += cnt[g];
        }
    }
    if (tid == 1023) off[N_NODES] = lds[1023];
}

__global__ __launch_bounds__(256) void k_reorder(const int* __restrict__ src,
                                                 const int* __restrict__ dst,
                                                 int* __restrict__ cursor,
                                                 int* __restrict__ srcs) {
    int e = blockIdx.x * 256 + threadIdx.x;
    if (e >= N_EDGES) return;
    int d = dst[e];
    int p = atomicAdd(&cursor[d], 1);
    srcs[p] = src[e];
}

// xn[i*16+c] = (c<13 ? x[i*13+c] : 0) * dis[i]
__global__ __launch_bounds__(256) void k_xn(const float* __restrict__ x,
                                            const float* __restrict__ dis,
                                            float* __restrict__ xn) {
    int idx = blockIdx.x * 256 + threadIdx.x;
    if (idx >= N_NODES * 16) return;
    int node = idx >> 4, c = idx & 15;
    float v = (c < IN_CH) ? x[node * IN_CH + c] * dis[node] : 0.f;
    xn[idx] = v;
}

// one wave per node; 16 ch x 4-way edge split; no atomics.
// outv[d*16+ch] = dis[d] * (sum_{edges} vin[s*16+ch] + vin[d*16+ch]) (+ bias)
__global__ __launch_bounds__(256) void k_agg(const int* __restrict__ off,
                                             const int* __restrict__ srcs,
                                             const float* __restrict__ dis,
                                             const float* __restrict__ vin,
                                             const float* __restrict__ bias,  // may be null
                                             float* __restrict__ outv) {
    int wave = (blockIdx.x * 256 + threadIdx.x) >> 6;
    int lane = threadIdx.x & 63;
    int ch = lane & 15, j = lane >> 4;
    if (wave >= N_NODES) return;
    int beg = off[wave], end = off[wave + 1];
    float acc = 0.f;
    for (int k = beg + j; k < end; k += 4)
        acc += vin[srcs[k] * 16 + ch];
    acc += __shfl_xor(acc, 16);
    acc += __shfl_xor(acc, 32);
    if (j == 0) {
        float r = dis[wave] * (acc + vin[wave * 16 + ch]);
        if (bias) r += bias[ch];
        outv[wave * 16 + ch] = r;
    }
}

// fused: hwn = (relu(s1 @ W1 + b1) @ W2) * dis   (per node, through LDS)
__global__ __launch_bounds__(256) void k_gemm12(const float* __restrict__ s1,
                                                const float* __restrict__ W1,
                                                const float* __restrict__ b1,
                                                const float* __restrict__ W2,
                                                const float* __restrict__ dis,
                                                float* __restrict__ hwn) {
    __shared__ float sW1[IN_CH * HID_CH];
    __shared__ float sW2[HID_CH * LAT_CH];
    __shared__ float sr[8][HID_CH + 1];
    int tid = threadIdx.x;
    for (int i = tid; i < IN_CH * HID_CH; i += 256) sW1[i] = W1[i];
    for (int i = tid; i < HID_CH * LAT_CH; i += 256) sW2[i] = W2[i];
    __syncthreads();
    int nl = tid >> 5, c1 = tid & 31;
    int node = blockIdx.x * 8 + nl;
    float r = 0.f;
    if (node < N_NODES) {
        float acc = b1[c1];
#pragma unroll
        for (int k = 0; k < IN_CH; ++k)
            acc += s1[node * 16 + k] * sW1[k * HID_CH + c1];
        r = acc > 0.f ? acc : 0.f;   // ReLU
    }
    sr[nl][c1] = r;
    __syncthreads();
    if (tid < 128) {
        int nl2 = tid >> 4, c2 = tid & 15;
        int node2 = blockIdx.x * 8 + nl2;
        if (node2 < N_NODES) {
            float acc = 0.f;
#pragma unroll
            for (int k = 0; k < HID_CH; ++k)
                acc += sr[nl2][k] * sW2[k * LAT_CH + c2];
            hwn[node2 * 16 + c2] = acc * dis[node2];
        }
    }
}

extern "C" void kernel_launch(void* const* d_in, const int* in_sizes, int n_in,
                              void* d_out, int out_size, void* d_ws, size_t ws_size,
                              hipStream_t stream) {
    const float* x  = (const float*)d_in[0];
    const int*   ei = (const int*)d_in[1];
    const float* W1 = (const float*)d_in[2];
    const float* b1 = (const float*)d_in[3];
    const float* W2 = (const float*)d_in[4];
    const float* b2 = (const float*)d_in[5];
    float* out = (float*)d_out;

    const int* src = ei;
    const int* dst = ei + N_EDGES;

    // ws layout (bytes):
    // cnt[N] | off[N+1] | cursor[N] | dis[N] | xn[N*16] | s1[N*16] | srcs[E]
    // hwn aliases xn (xn dead after k_agg1). Total ~27.2 MB.
    char* ws = (char*)d_ws;
    int*   cnt    = (int*)(ws);
    int*   off    = (int*)(ws + 400000);
    int*   cursor = (int*)(ws + 400000 + 400016);
    float* dis    = (float*)(ws + 2 * 400000 + 400016);
    float* xn     = (float*)(ws + 3 * 400000 + 400016);
    float* s1     = (float*)(ws + 3 * 400000 + 400016 + 6400000);
    int*   srcs   = (int*)  (ws + 3 * 400000 + 400016 + 2 * 6400000);
    float* hwn    = xn;  // alias: xn dead after k_agg1

    const int NB_N  = (N_NODES + 255) / 256;
    const int NB_E  = (N_EDGES + 255) / 256;
    const int NB_N16= (N_NODES * 16 + 255) / 256;
    const int NB_W  = (N_NODES + 3) / 4;       // 1 wave per node, 4 waves/block
    const int NB_G  = (N_NODES + 7) / 8;       // 8 nodes per block

    k_zero   <<<NB_N,  256, 0, stream>>>(cnt);
    k_hist   <<<NB_E,  256, 0, stream>>>(dst, cnt);
    k_dis    <<<NB_N,  256, 0, stream>>>(cnt, dis);
    k_scan   <<<1,    1024, 0, stream>>>(cnt, off, cursor);
    k_reorder<<<NB_E,  256, 0, stream>>>(src, dst, cursor, srcs);
    k_xn     <<<NB_N16,256, 0, stream>>>(x, dis, xn);
    k_agg    <<<NB_W,  256, 0, stream>>>(off, srcs, dis, xn, nullptr, s1);   // layer-1 agg
    k_gemm12 <<<NB_G,  256, 0, stream>>>(s1, W1, b1, W2, dis, hwn);
    k_agg    <<<NB_W,  256, 0, stream>>>(off, srcs, dis, hwn, b2, out);      // layer-2 agg
}

// Round 3
// 330.074 us; speedup vs baseline: 2.8717x; 2.8717x over previous
//
#include <hip/hip_runtime.h>

// GCN 2-layer, N=100000, E=3200000, 13 -> 32 -> 16.
// Two-level counting sort by dst (coarse buckets of 512 nodes -> per-bucket
// LDS counting sort), then atomic-free per-node aggregation.
// Layer 1 aggregates BEFORE the GEMM (linearity): 16-ch messages both layers.
// Aggregation inputs pre-multiplied by dis[src]; dis[dst] applied per node.

constexpr int N_NODES = 100000;
constexpr int N_EDGES = 3200000;
constexpr int IN_CH  = 13;
constexpr int HID_CH = 32;
constexpr int LAT_CH = 16;

constexpr int NBKT = 196;        // ceil(100000/512) coarse buckets (dst>>9)
constexpr int BCAP = 20480;      // bucket capacity; mean 16384, sd ~128 -> 32 sigma
constexpr int TILE = 16384;      // edges per binA block

__global__ __launch_bounds__(256) void k_zero_bcur(int* __restrict__ bcur) {
    int i = threadIdx.x;
    if (i < NBKT) bcur[i] = 0;
}

// bin edges into coarse bucket regions; packed word = (dst&511)<<17 | src
__global__ __launch_bounds__(1024) void k_binA(const int* __restrict__ src,
                                               const int* __restrict__ dst,
                                               int* __restrict__ bcur,
                                               int* __restrict__ buckets) {
    __shared__ int h[NBKT], st[NBKT], cur[NBKT];
    int tid = threadIdx.x;
    for (int i = tid; i < NBKT; i += 1024) h[i] = 0;
    __syncthreads();
    int e0 = blockIdx.x * TILE;
    for (int i = tid; i < TILE; i += 1024) {
        int e = e0 + i;
        if (e < N_EDGES) atomicAdd(&h[dst[e] >> 9], 1);
    }
    __syncthreads();
    for (int i = tid; i < NBKT; i += 1024) {
        int c = h[i];
        st[i] = c > 0 ? atomicAdd(&bcur[i], c) : 0;
        cur[i] = 0;
    }
    __syncthreads();
    for (int i = tid; i < TILE; i += 1024) {
        int e = e0 + i;
        if (e < N_EDGES) {
            int d = dst[e];
            int b = d >> 9;
            int r = atomicAdd(&cur[b], 1);
            buckets[b * BCAP + st[b] + r] = src[e] | ((d & 511) << 17);
        }
    }
}

// exclusive scan of 196 bucket counts (one tiny block)
__global__ __launch_bounds__(256) void k_scanTop(const int* __restrict__ bcur,
                                                 int* __restrict__ bbase) {
    __shared__ int v[256];
    int tid = threadIdx.x;
    v[tid] = (tid < NBKT) ? bcur[tid] : 0;
    __syncthreads();
    for (int d = 1; d < 256; d <<= 1) {
        int a = v[tid];
        int u = (tid >= d) ? v[tid - d] : 0;
        __syncthreads();
        v[tid] = a + u;
        __syncthreads();
    }
    if (tid < NBKT) bbase[tid] = v[tid] - bcur[tid];
}

// per-bucket counting sort: LDS hist over 512 nodes -> LDS scan -> scatter.
// also emits off[node], dis[node].
__global__ __launch_bounds__(1024) void k_binB(const int* __restrict__ bcur,
                                               const int* __restrict__ bbase,
                                               const int* __restrict__ buckets,
                                               int* __restrict__ off,
                                               float* __restrict__ dis,
                                               int* __restrict__ srcs) {
    __shared__ int h[512], ex[512], curso[512];
    int b = blockIdx.x, tid = threadIdx.x;
    int cntb = bcur[b], base = bbase[b];
    const int* bw = buckets + b * BCAP;
    if (tid < 512) h[tid] = 0;
    __syncthreads();
    for (int i = tid; i < cntb; i += 1024) atomicAdd(&h[bw[i] >> 17], 1);
    __syncthreads();
    int node0 = b * 512;
    if (tid < 512) {
        int node = node0 + tid;
        if (node < N_NODES) dis[node] = rsqrtf((float)(h[tid] + 1));  // +1 self-loop
        ex[tid] = h[tid];
    }
    __syncthreads();
    for (int d = 1; d < 512; d <<= 1) {    // inclusive scan over 512
        int a = 0, u = 0;
        if (tid < 512) a = ex[tid];
        if (tid >= d && tid < 512) u = ex[tid - d];
        __syncthreads();
        if (tid < 512) ex[tid] = a + u;
        __syncthreads();
    }
    if (tid < 512) {
        int excl = ex[tid] - h[tid];
        int node = node0 + tid;
        if (node < N_NODES) off[node] = base + excl;
        curso[tid] = excl;
    }
    if (b == 0 && tid == 0) off[N_NODES] = N_EDGES;
    __syncthreads();
    for (int i = tid; i < cntb; i += 1024) {
        int w = bw[i];
        int r = atomicAdd(&curso[w >> 17], 1);
        srcs[base + r] = w & 131071;
    }
}

// xn[i*16+c] = (c<13 ? x[i*13+c] : 0) * dis[i]
__global__ __launch_bounds__(256) void k_xn(const float* __restrict__ x,
                                            const float* __restrict__ dis,
                                            float* __restrict__ xn) {
    int idx = blockIdx.x * 256 + threadIdx.x;
    if (idx >= N_NODES * 16) return;
    int node = idx >> 4, c = idx & 15;
    xn[idx] = (c < IN_CH) ? x[node * IN_CH + c] * dis[node] : 0.f;
}

// one wave per node; 16 ch x 4-way edge split; no atomics.
// outv[d*16+ch] = dis[d] * (sum_edges vin[s*16+ch] + vin[d*16+ch]) (+ bias)
__global__ __launch_bounds__(256) void k_agg(const int* __restrict__ off,
                                             const int* __restrict__ srcs,
                                             const float* __restrict__ dis,
                                             const float* __restrict__ vin,
                                             const float* __restrict__ bias,  // may be null
                                             float* __restrict__ outv) {
    int wave = (blockIdx.x * 256 + threadIdx.x) >> 6;
    int lane = threadIdx.x & 63;
    int ch = lane & 15, j = lane >> 4;
    if (wave >= N_NODES) return;
    int beg = off[wave], end = off[wave + 1];
    float acc = 0.f;
    for (int k = beg + j; k < end; k += 4)
        acc += vin[srcs[k] * 16 + ch];
    acc += __shfl_xor(acc, 16);
    acc += __shfl_xor(acc, 32);
    if (j == 0) {
        float r = dis[wave] * (acc + vin[wave * 16 + ch]);
        if (bias) r += bias[ch];
        outv[wave * 16 + ch] = r;
    }
}

// fused: hwn = (relu(s1 @ W1 + b1) @ W2) * dis   (per node, through LDS)
__global__ __launch_bounds__(256) void k_gemm12(const float* __restrict__ s1,
                                                const float* __restrict__ W1,
                                                const float* __restrict__ b1,
                                                const float* __restrict__ W2,
                                                const float* __restrict__ dis,
                                                float* __restrict__ hwn) {
    __shared__ float sW1[IN_CH * HID_CH];
    __shared__ float sW2[HID_CH * LAT_CH];
    __shared__ float sr[8][HID_CH + 1];
    int tid = threadIdx.x;
    for (int i = tid; i < IN_CH * HID_CH; i += 256) sW1[i] = W1[i];
    for (int i = tid; i < HID_CH * LAT_CH; i += 256) sW2[i] = W2[i];
    __syncthreads();
    int nl = tid >> 5, c1 = tid & 31;
    int node = blockIdx.x * 8 + nl;
    float r = 0.f;
    if (node < N_NODES) {
        float acc = b1[c1];
#pragma unroll
        for (int k = 0; k < IN_CH; ++k)
            acc += s1[node * 16 + k] * sW1[k * HID_CH + c1];
        r = acc > 0.f ? acc : 0.f;   // ReLU
    }
    sr[nl][c1] = r;
    __syncthreads();
    if (tid < 128) {
        int nl2 = tid >> 4, c2 = tid & 15;
        int node2 = blockIdx.x * 8 + nl2;
        if (node2 < N_NODES) {
            float acc = 0.f;
#pragma unroll
            for (int k = 0; k < HID_CH; ++k)
                acc += sr[nl2][k] * sW2[k * LAT_CH + c2];
            hwn[node2 * 16 + c2] = acc * dis[node2];
        }
    }
}

extern "C" void kernel_launch(void* const* d_in, const int* in_sizes, int n_in,
                              void* d_out, int out_size, void* d_ws, size_t ws_size,
                              hipStream_t stream) {
    const float* x  = (const float*)d_in[0];
    const int*   ei = (const int*)d_in[1];
    const float* W1 = (const float*)d_in[2];
    const float* b1 = (const float*)d_in[3];
    const float* W2 = (const float*)d_in[4];
    const float* b2 = (const float*)d_in[5];
    float* out = (float*)d_out;

    const int* src = ei;
    const int* dst = ei + N_EDGES;

    // ws layout (bytes):
    //   bcur[196]    @ 0          (1024)
    //   bbase[196]   @ 1024       (1024)
    //   off[N+1]     @ 2048       (400016)
    //   dis[N]       @ 402064->pad 402176 (400000)
    //   srcs[E]      @ 802176     (12800000)
    //   buckets      @ 13602176   (196*20480*4 = 16056320)  -- dead after binB
    //   xn  aliases buckets       (6400000)
    //   s1  aliases buckets+6.4MB (6400000)
    // total ~29.7 MB
    char* ws = (char*)d_ws;
    int*   bcur    = (int*)(ws);
    int*   bbase   = (int*)(ws + 1024);
    int*   off     = (int*)(ws + 2048);
    float* dis     = (float*)(ws + 402176);
    int*   srcs    = (int*)(ws + 802176);
    int*   buckets = (int*)(ws + 13602176);
    float* xn      = (float*)(ws + 13602176);
    float* s1      = (float*)(ws + 13602176 + 6400000);
    float* hwn     = xn;  // xn dead after first k_agg

    const int NB_A  = (N_EDGES + TILE - 1) / TILE;      // 196
    const int NB_N16= (N_NODES * 16 + 255) / 256;
    const int NB_W  = (N_NODES + 3) / 4;                // 1 wave/node, 4 waves/block
    const int NB_G  = (N_NODES + 7) / 8;

    k_zero_bcur<<<1,    256, 0, stream>>>(bcur);
    k_binA     <<<NB_A, 1024, 0, stream>>>(src, dst, bcur, buckets);
    k_scanTop  <<<1,    256, 0, stream>>>(bcur, bbase);
    k_binB     <<<NBKT, 1024, 0, stream>>>(bcur, bbase, buckets, off, dis, srcs);
    k_xn       <<<NB_N16, 256, 0, stream>>>(x, dis, xn);
    k_agg      <<<NB_W,  256, 0, stream>>>(off, srcs, dis, xn, nullptr, s1);
    k_gemm12   <<<NB_G,  256, 0, stream>>>(s1, W1, b1, W2, dis, hwn);
    k_agg      <<<NB_W,  256, 0, stream>>>(off, srcs, dis, hwn, b2, out);
}

// Round 4
// 251.977 us; speedup vs baseline: 3.7617x; 1.3099x over previous
//
#include <hip/hip_runtime.h>

// GCN 2-layer, N=100000, E=3200000, 13 -> 32 -> 16.
// Two-level counting sort by dst, then atomic-free per-node aggregation.
// k_agg: 1 wave/node, 16 edges in flight (float4/lane), srcs prefetch pipeline.

constexpr int N_NODES = 100000;
constexpr int N_EDGES = 3200000;
constexpr int IN_CH  = 13;
constexpr int HID_CH = 32;
constexpr int LAT_CH = 16;

constexpr int NBKT = 196;        // ceil(100000/512) coarse buckets (dst>>9)
constexpr int BCAP = 20480;      // bucket capacity; mean 16384, sd ~128
constexpr int TILE = 16384;      // edges per binA block

__global__ __launch_bounds__(256) void k_zero_bcur(int* __restrict__ bcur) {
    int i = threadIdx.x;
    if (i < NBKT) bcur[i] = 0;
}

// bin edges into coarse bucket regions; packed word = (dst&511)<<17 | src
__global__ __launch_bounds__(1024) void k_binA(const int* __restrict__ src,
                                               const int* __restrict__ dst,
                                               int* __restrict__ bcur,
                                               int* __restrict__ buckets) {
    __shared__ int h[NBKT], st[NBKT], cur[NBKT];
    int tid = threadIdx.x;
    for (int i = tid; i < NBKT; i += 1024) h[i] = 0;
    __syncthreads();
    int e0 = blockIdx.x * TILE;
    for (int i = tid; i < TILE; i += 1024) {
        int e = e0 + i;
        if (e < N_EDGES) atomicAdd(&h[dst[e] >> 9], 1);
    }
    __syncthreads();
    for (int i = tid; i < NBKT; i += 1024) {
        int c = h[i];
        st[i] = c > 0 ? atomicAdd(&bcur[i], c) : 0;
        cur[i] = 0;
    }
    __syncthreads();
    for (int i = tid; i < TILE; i += 1024) {
        int e = e0 + i;
        if (e < N_EDGES) {
            int d = dst[e];
            int b = d >> 9;
            int r = atomicAdd(&cur[b], 1);
            buckets[b * BCAP + st[b] + r] = src[e] | ((d & 511) << 17);
        }
    }
}

// exclusive scan of 196 bucket counts (one tiny block)
__global__ __launch_bounds__(256) void k_scanTop(const int* __restrict__ bcur,
                                                 int* __restrict__ bbase) {
    __shared__ int v[256];
    int tid = threadIdx.x;
    v[tid] = (tid < NBKT) ? bcur[tid] : 0;
    __syncthreads();
    for (int d = 1; d < 256; d <<= 1) {
        int a = v[tid];
        int u = (tid >= d) ? v[tid - d] : 0;
        __syncthreads();
        v[tid] = a + u;
        __syncthreads();
    }
    if (tid < NBKT) bbase[tid] = v[tid] - bcur[tid];
}

// per-bucket counting sort: LDS hist over 512 nodes -> LDS scan -> scatter.
// also emits off[node], dis[node].
__global__ __launch_bounds__(1024) void k_binB(const int* __restrict__ bcur,
                                               const int* __restrict__ bbase,
                                               const int* __restrict__ buckets,
                                               int* __restrict__ off,
                                               float* __restrict__ dis,
                                               int* __restrict__ srcs) {
    __shared__ int h[512], ex[512], curso[512];
    int b = blockIdx.x, tid = threadIdx.x;
    int cntb = bcur[b], base = bbase[b];
    const int* bw = buckets + b * BCAP;
    if (tid < 512) h[tid] = 0;
    __syncthreads();
    for (int i = tid; i < cntb; i += 1024) atomicAdd(&h[bw[i] >> 17], 1);
    __syncthreads();
    int node0 = b * 512;
    if (tid < 512) {
        int node = node0 + tid;
        if (node < N_NODES) dis[node] = rsqrtf((float)(h[tid] + 1));  // +1 self-loop
        ex[tid] = h[tid];
    }
    __syncthreads();
    for (int d = 1; d < 512; d <<= 1) {    // inclusive scan over 512
        int a = 0, u = 0;
        if (tid < 512) a = ex[tid];
        if (tid >= d && tid < 512) u = ex[tid - d];
        __syncthreads();
        if (tid < 512) ex[tid] = a + u;
        __syncthreads();
    }
    if (tid < 512) {
        int excl = ex[tid] - h[tid];
        int node = node0 + tid;
        if (node < N_NODES) off[node] = base + excl;
        curso[tid] = excl;
    }
    if (b == 0 && tid == 0) off[N_NODES] = N_EDGES;
    __syncthreads();
    for (int i = tid; i < cntb; i += 1024) {
        int w = bw[i];
        int r = atomicAdd(&curso[w >> 17], 1);
        srcs[base + r] = w & 131071;
    }
}

// xn[i*16+c] = (c<13 ? x[i*13+c] : 0) * dis[i]
__global__ __launch_bounds__(256) void k_xn(const float* __restrict__ x,
                                            const float* __restrict__ dis,
                                            float* __restrict__ xn) {
    int idx = blockIdx.x * 256 + threadIdx.x;
    if (idx >= N_NODES * 16) return;
    int node = idx >> 4, c = idx & 15;
    xn[idx] = (c < IN_CH) ? x[node * IN_CH + c] * dis[node] : 0.f;
}

// 1 wave per node; 16 edge slots x 4 channel-quads (float4/lane); no atomics.
// srcs for iteration i+1 prefetched before consuming gather i.
// outv[d*16+ch] = dis[d] * (sum_edges vin[s*16+ch] + vin[d*16+ch]) (+ bias)
__global__ __launch_bounds__(256) void k_agg(const int* __restrict__ off,
                                             const int* __restrict__ srcs,
                                             const float* __restrict__ dis,
                                             const float* __restrict__ vin,
                                             const float* __restrict__ bias,  // may be null
                                             float* __restrict__ outv) {
    int wave = (blockIdx.x * 256 + threadIdx.x) >> 6;
    int lane = threadIdx.x & 63;
    int q    = lane & 3;       // channel quad: floats q*4 .. q*4+3
    int esub = lane >> 2;      // edge slot 0..15
    if (wave >= N_NODES) return;
    int beg = off[wave], end = off[wave + 1];

    float ax = 0.f, ay = 0.f, az = 0.f, aw = 0.f;
    int k = beg + esub;
    int s = (k < end) ? srcs[k] : -1;
    for (int kb = beg; kb < end; kb += 16) {
        int kn = kb + 16 + esub;
        int sn = (kn < end) ? srcs[kn] : -1;   // prefetch next iteration's index
        if (s >= 0) {
            const float4 v = *((const float4*)(vin + (size_t)s * 16) + q);
            ax += v.x; ay += v.y; az += v.z; aw += v.w;
        }
        s = sn;
    }
#pragma unroll
    for (int m = 4; m <= 32; m <<= 1) {        // reduce over esub (lane bits 2..5)
        ax += __shfl_xor(ax, m);
        ay += __shfl_xor(ay, m);
        az += __shfl_xor(az, m);
        aw += __shfl_xor(aw, m);
    }
    if (esub == 0) {
        const float4 self = *((const float4*)(vin + (size_t)wave * 16) + q);
        float d = dis[wave];
        float4 r;
        r.x = d * (ax + self.x);
        r.y = d * (ay + self.y);
        r.z = d * (az + self.z);
        r.w = d * (aw + self.w);
        if (bias) {
            const float4 bq = ((const float4*)bias)[q];
            r.x += bq.x; r.y += bq.y; r.z += bq.z; r.w += bq.w;
        }
        *((float4*)(outv + (size_t)wave * 16) + q) = r;
    }
}

// fused: hwn = (relu(s1 @ W1 + b1) @ W2) * dis   (per node, through LDS)
__global__ __launch_bounds__(256) void k_gemm12(const float* __restrict__ s1,
                                                const float* __restrict__ W1,
                                                const float* __restrict__ b1,
                                                const float* __restrict__ W2,
                                                const float* __restrict__ dis,
                                                float* __restrict__ hwn) {
    __shared__ float sW1[IN_CH * HID_CH];
    __shared__ float sW2[HID_CH * LAT_CH];
    __shared__ float sr[8][HID_CH + 1];
    int tid = threadIdx.x;
    for (int i = tid; i < IN_CH * HID_CH; i += 256) sW1[i] = W1[i];
    for (int i = tid; i < HID_CH * LAT_CH; i += 256) sW2[i] = W2[i];
    __syncthreads();
    int nl = tid >> 5, c1 = tid & 31;
    int node = blockIdx.x * 8 + nl;
    float r = 0.f;
    if (node < N_NODES) {
        float acc = b1[c1];
#pragma unroll
        for (int k = 0; k < IN_CH; ++k)
            acc += s1[node * 16 + k] * sW1[k * HID_CH + c1];
        r = acc > 0.f ? acc : 0.f;   // ReLU
    }
    sr[nl][c1] = r;
    __syncthreads();
    if (tid < 128) {
        int nl2 = tid >> 4, c2 = tid & 15;
        int node2 = blockIdx.x * 8 + nl2;
        if (node2 < N_NODES) {
            float acc = 0.f;
#pragma unroll
            for (int k = 0; k < HID_CH; ++k)
                acc += sr[nl2][k] * sW2[k * LAT_CH + c2];
            hwn[node2 * 16 + c2] = acc * dis[node2];
        }
    }
}

extern "C" void kernel_launch(void* const* d_in, const int* in_sizes, int n_in,
                              void* d_out, int out_size, void* d_ws, size_t ws_size,
                              hipStream_t stream) {
    const float* x  = (const float*)d_in[0];
    const int*   ei = (const int*)d_in[1];
    const float* W1 = (const float*)d_in[2];
    const float* b1 = (const float*)d_in[3];
    const float* W2 = (const float*)d_in[4];
    const float* b2 = (const float*)d_in[5];
    float* out = (float*)d_out;

    const int* src = ei;
    const int* dst = ei + N_EDGES;

    // ws layout (bytes):
    //   bcur[196]  @ 0        | bbase[196] @ 1024 | off[N+1] @ 2048
    //   dis[N]     @ 402176   | srcs[E]    @ 802176
    //   buckets    @ 13602176 (196*20480*4) -- dead after binB
    //   xn  aliases buckets; s1 aliases buckets+6.4MB; hwn aliases xn
    char* ws = (char*)d_ws;
    int*   bcur    = (int*)(ws);
    int*   bbase   = (int*)(ws + 1024);
    int*   off     = (int*)(ws + 2048);
    float* dis     = (float*)(ws + 402176);
    int*   srcs    = (int*)(ws + 802176);
    int*   buckets = (int*)(ws + 13602176);
    float* xn      = (float*)(ws + 13602176);
    float* s1      = (float*)(ws + 13602176 + 6400000);
    float* hwn     = xn;  // xn dead after first k_agg

    const int NB_A  = (N_EDGES + TILE - 1) / TILE;      // 196
    const int NB_N16= (N_NODES * 16 + 255) / 256;
    const int NB_W  = (N_NODES + 3) / 4;                // 1 wave/node, 4 waves/block
    const int NB_G  = (N_NODES + 7) / 8;

    k_zero_bcur<<<1,    256, 0, stream>>>(bcur);
    k_binA     <<<NB_A, 1024, 0, stream>>>(src, dst, bcur, buckets);
    k_scanTop  <<<1,    256, 0, stream>>>(bcur, bbase);
    k_binB     <<<NBKT, 1024, 0, stream>>>(bcur, bbase, buckets, off, dis, srcs);
    k_xn       <<<NB_N16, 256, 0, stream>>>(x, dis, xn);
    k_agg      <<<NB_W,  256, 0, stream>>>(off, srcs, dis, xn, nullptr, s1);
    k_gemm12   <<<NB_G,  256, 0, stream>>>(s1, W1, b1, W2, dis, hwn);
    k_agg      <<<NB_W,  256, 0, stream>>>(off, srcs, dis, hwn, b2, out);
}